// Round 4
// baseline (525.598 us; speedup 1.0000x reference)
//
#include <hip/hip_runtime.h>
#include <hip/hip_bf16.h>

#define M_ROWS 256
#define T_LEN  1024
#define NLAG   2048
#define GSTRIDE 2072   // 2048 + 24 tail; word stride 1036 ≡ 12 mod 32 -> copies on disjoint banks

typedef __attribute__((ext_vector_type(8)))  __bf16 bf16x8;
typedef __attribute__((ext_vector_type(16))) float  f32x16;
typedef __attribute__((ext_vector_type(4)))  unsigned int u32x4;

static __device__ __forceinline__ unsigned short f2bf(float f) {
  unsigned int u = __builtin_bit_cast(unsigned int, f);
  u += 0x7FFFu + ((u >> 16) & 1u);   // RNE
  return (unsigned short)(u >> 16);
}

// ---------------- prep: center rows, bf16-ify, std(ddof=1) ----------------
// f1 -> packed fragment layout f1p[kg][row][8]  (kg = k/8), f2 -> row-major
__global__ __launch_bounds__(256) void prep_kernel(
    const float* __restrict__ zis, const float* __restrict__ zjs,
    unsigned short* __restrict__ f1p, unsigned short* __restrict__ f2c,
    float* __restrict__ s1, float* __restrict__ s2) {
  int r = blockIdx.x;  // 0..511
  const float* src = (r < M_ROWS) ? (zis + r * T_LEN) : (zjs + (r - M_ROWS) * T_LEN);
  int t = threadIdx.x;
  float4 v = reinterpret_cast<const float4*>(src)[t];
  float ls = v.x + v.y + v.z + v.w;
  for (int m = 1; m <= 32; m <<= 1) ls += __shfl_xor(ls, m, 64);
  __shared__ float red[4];
  __shared__ float red2[4];
  if ((t & 63) == 0) red[t >> 6] = ls;
  __syncthreads();
  float mean = (red[0] + red[1] + red[2] + red[3]) * (1.0f / 1024.0f);
  float c0 = v.x - mean, c1 = v.y - mean, c2 = v.z - mean, c3 = v.w - mean;
  float ss = c0 * c0 + c1 * c1 + c2 * c2 + c3 * c3;
  for (int m = 1; m <= 32; m <<= 1) ss += __shfl_xor(ss, m, 64);
  if ((t & 63) == 0) red2[t >> 6] = ss;
  __syncthreads();
  float sd = sqrtf((red2[0] + red2[1] + red2[2] + red2[3]) * (1.0f / 1023.0f));
  ushort4 o;
  o.x = f2bf(c0); o.y = f2bf(c1); o.z = f2bf(c2); o.w = f2bf(c3);
  if (r < M_ROWS) {
    if (t == 0) s1[r] = sd;
    reinterpret_cast<ushort4*>(&f1p[(((t >> 1) * 256) + r) * 8 + (t & 1) * 4])[0] = o;
  } else {
    if (t == 0) s2[r - M_ROWS] = sd;
    reinterpret_cast<ushort4*>(&f2c[(r - M_ROWS) * T_LEN + 4 * t])[0] = o;
  }
}

#define LOAD_A(A0, A1, A2, A3)                                   \
  {                                                              \
    A0 = *reinterpret_cast<const bf16x8*>(ap);                   \
    A1 = *reinterpret_cast<const bf16x8*>(ap + 256);             \
    A2 = *reinterpret_cast<const bf16x8*>(ap + 4096);            \
    A3 = *reinterpret_cast<const bf16x8*>(ap + 4096 + 256);      \
    ap += 8192;                                                  \
  }

#define LOAD_B(B0, B1, B2, B3, KS)                               \
  {                                                              \
    int y0 = (yc0 + (KS) * 32) & (NLAG - 1);                     \
    int y1 = (yc1 + (KS) * 32) & (NLAG - 1);                     \
    const unsigned short* bp0 = &gall[bb + y0];                  \
    const unsigned short* bp1 = &gall[bb + y1];                  \
    B0 = *reinterpret_cast<const bf16x8*>(bp0);                  \
    B1 = *reinterpret_cast<const bf16x8*>(bp0 + 16);             \
    B2 = *reinterpret_cast<const bf16x8*>(bp1);                  \
    B3 = *reinterpret_cast<const bf16x8*>(bp1 + 16);             \
  }

#define MFMA_SET(A0, A1, A2, A3, B0, B1, B2, B3)                                   \
  {                                                                                \
    acc00 = __builtin_amdgcn_mfma_f32_32x32x16_bf16(A0, B0, acc00, 0, 0, 0);       \
    acc01 = __builtin_amdgcn_mfma_f32_32x32x16_bf16(A0, B2, acc01, 0, 0, 0);       \
    acc10 = __builtin_amdgcn_mfma_f32_32x32x16_bf16(A1, B0, acc10, 0, 0, 0);       \
    acc11 = __builtin_amdgcn_mfma_f32_32x32x16_bf16(A1, B2, acc11, 0, 0, 0);       \
    acc00 = __builtin_amdgcn_mfma_f32_32x32x16_bf16(A2, B1, acc00, 0, 0, 0);       \
    acc01 = __builtin_amdgcn_mfma_f32_32x32x16_bf16(A2, B3, acc01, 0, 0, 0);       \
    acc10 = __builtin_amdgcn_mfma_f32_32x32x16_bf16(A3, B1, acc10, 0, 0, 0);       \
    acc11 = __builtin_amdgcn_mfma_f32_32x32x16_bf16(A3, B3, acc11, 0, 0, 0);       \
  }

// ---------------- Toeplitz-GEMM correlation + per-row lag-max ----------------
// grid: wg = (chunk*2 + iblk)*256 + j ; 2048 wgs, 256 threads (4 waves, wy x wx)
__global__ __launch_bounds__(256, 2) void corr_kernel(
    const unsigned short* __restrict__ f1p,
    const unsigned short* __restrict__ f2c,
    float* __restrict__ part) {
  __shared__ __align__(16) unsigned short gall[8 * GSTRIDE];  // 33152 B
  __shared__ float red[2][128];                               // 1024 B

  int wg = blockIdx.x;
  int j = wg & 255;
  int iblk = (wg >> 8) & 1;
  int chunk = wg >> 9;  // 0..3

  int tid = threadIdx.x;
  int lane = tid & 63;
  int w = tid >> 6;
  int wx = w & 1;   // lag half
  int wy = w >> 1;  // row half
  int l5 = lane >> 5;
  int lq = (lane >> 3) & 3;
  int lr = lane & 7;
  int l31 = lane & 31;

  // ---- step A: copy 0 = centered f2 row, zero-padded, +24-elem wrap tail ----
  {
    const unsigned short* f2row = f2c + j * T_LEN;
    if (tid < 128) {
      u32x4 v = *reinterpret_cast<const u32x4*>(f2row + tid * 8);
      *reinterpret_cast<u32x4*>(&gall[tid * 8]) = v;
    } else {
      u32x4 z; z[0] = z[1] = z[2] = z[3] = 0;
      *reinterpret_cast<u32x4*>(&gall[1024 + (tid - 128) * 8]) = z;
      if (tid < 131) {
        u32x4 v = *reinterpret_cast<const u32x4*>(f2row + (tid - 128) * 8);
        *reinterpret_cast<u32x4*>(&gall[2048 + (tid - 128) * 8]) = v;
      }
    }
  }
  __syncthreads();

  // ---- step B: copies r=1..7 via aligned b128 reads + compile-time funnel shift ----
  {
    const unsigned int* g0w = reinterpret_cast<const unsigned int*>(gall);
#pragma unroll
    for (int r = 1; r < 8; ++r) {
      const int kk = (8 - r) >> 1;   // uniform: base bits[2:1]
      for (int c = tid; c < 259; c += 256) {
        int base = (c * 8 - r) & (NLAG - 1);
        int wa = (base >> 1) - kk;   // 4-aligned
        u32x4 W0 = *reinterpret_cast<const u32x4*>(&g0w[wa]);
        u32x4 W1 = *reinterpret_cast<const u32x4*>(&g0w[wa + 4]);
        unsigned int wv[8] = {W0[0], W0[1], W0[2], W0[3], W1[0], W1[1], W1[2], W1[3]};
        u32x4 ow;
        if (r & 1) {
#pragma unroll
          for (int i = 0; i < 4; ++i)
            ow[i] = (wv[kk + i] >> 16) | (wv[kk + i + 1] << 16);
        } else {
#pragma unroll
          for (int i = 0; i < 4; ++i) ow[i] = wv[kk + i];
        }
        *reinterpret_cast<u32x4*>(&gall[r * GSTRIDE + c * 8]) = ow;
      }
    }
  }
  __syncthreads();

  int rowb = iblk * 128 + wy * 64;
  // A base: element ((ks*4 + ksub*2 + l5)*256 + row)*8
  const unsigned short* abase = f1p + ((l5 * 256) + rowb + l31) * 8;
  int bb = lr * GSTRIDE;
  int ycb = 8 * l5 - 8 * lq - wx * 64;

  float pm0[16], pm1[16];
#pragma unroll
  for (int q = 0; q < 16; ++q) { pm0[q] = -3.4e38f; pm1[q] = -3.4e38f; }

  for (int tb = 0; tb < 4; ++tb) {
    int tau0 = tb * 512 + chunk * 128;  // strided for load balance
    int kA, kB;
    if (tau0 < 1024) { kA = tau0 >> 5; kB = 32; }
    else             { kA = 0;         kB = ((tau0 - 898) >> 5) + 1; }
    // kB - kA is always even and >= 4

    int yc0 = ycb - tau0;
    int yc1 = yc0 - 32;

    f32x16 acc00, acc01, acc10, acc11;
#pragma unroll
    for (int q = 0; q < 16; ++q) { acc00[q] = 0.f; acc01[q] = 0.f; acc10[q] = 0.f; acc11[q] = 0.f; }

    const unsigned short* ap = abase + kA * 8192;

    // register double-buffer software pipeline (2 fragment sets X/Y)
    bf16x8 xa0, xa1, xa2, xa3, xb0, xb1, xb2, xb3;
    bf16x8 ya0, ya1, ya2, ya3, yb0, yb1, yb2, yb3;

    LOAD_A(xa0, xa1, xa2, xa3);
    LOAD_B(xb0, xb1, xb2, xb3, kA);

    int ks = kA;
#pragma unroll 1
    for (; ks < kB - 2; ks += 2) {
      LOAD_A(ya0, ya1, ya2, ya3);
      LOAD_B(yb0, yb1, yb2, yb3, ks + 1);
      MFMA_SET(xa0, xa1, xa2, xa3, xb0, xb1, xb2, xb3);
      LOAD_A(xa0, xa1, xa2, xa3);
      LOAD_B(xb0, xb1, xb2, xb3, ks + 2);
      MFMA_SET(ya0, ya1, ya2, ya3, yb0, yb1, yb2, yb3);
    }
    // tail: ks == kB-2; X holds ks, load Y for ks+1
    LOAD_A(ya0, ya1, ya2, ya3);
    LOAD_B(yb0, yb1, yb2, yb3, ks + 1);
    MFMA_SET(xa0, xa1, xa2, xa3, xb0, xb1, xb2, xb3);
    MFMA_SET(ya0, ya1, ya2, ya3, yb0, yb1, yb2, yb3);

    // fold this tau-block into the per-lane running max (registers only)
#pragma unroll
    for (int q = 0; q < 16; ++q) {
      pm0[q] = fmaxf(pm0[q], fmaxf(acc00[q], acc01[q]));
      pm1[q] = fmaxf(pm1[q], fmaxf(acc10[q], acc11[q]));
    }
  }

  // single cross-lane reduction per wg
#pragma unroll
  for (int rf = 0; rf < 2; ++rf) {
#pragma unroll
    for (int q = 0; q < 16; ++q) {
      float v = rf ? pm1[q] : pm0[q];
      v = fmaxf(v, __shfl_xor(v, 1, 64));
      v = fmaxf(v, __shfl_xor(v, 2, 64));
      v = fmaxf(v, __shfl_xor(v, 4, 64));
      v = fmaxf(v, __shfl_xor(v, 8, 64));
      v = fmaxf(v, __shfl_xor(v, 16, 64));
      if (l31 == 0) red[wx][wy * 64 + rf * 32 + (q & 3) + 8 * (q >> 2) + 4 * l5] = v;
    }
  }
  __syncthreads();
  if (tid < 128)
    part[(j * 4 + chunk) * 256 + iblk * 128 + tid] = fmaxf(red[0][tid], red[1][tid]);
}

// ---------------- per-row CE: dist, logsumexp, pick target ----------------
__global__ __launch_bounds__(256) void loss_kernel(
    const float* __restrict__ part, const float* __restrict__ s1,
    const float* __restrict__ s2, const int* __restrict__ speeds,
    float* __restrict__ lossrows) {
  int i = blockIdx.x;
  int jt = threadIdx.x;
  float m = part[(jt * 4 + 0) * 256 + i];
  m = fmaxf(m, part[(jt * 4 + 1) * 256 + i]);
  m = fmaxf(m, part[(jt * 4 + 2) * 256 + i]);
  m = fmaxf(m, part[(jt * 4 + 3) * 256 + i]);
  float p = s1[i] * s2[jt];
  p = (p == 0.0f) ? 1.0f : p;
  float d = m / (p * 1023.0f);

  float t = d;
  for (int mk = 1; mk <= 32; mk <<= 1) t = fmaxf(t, __shfl_xor(t, mk, 64));
  __shared__ float wmax[4], wsum[4], sel;
  if ((jt & 63) == 0) wmax[jt >> 6] = t;
  if (jt == speeds[i]) sel = d;
  __syncthreads();
  float rmax = fmaxf(fmaxf(wmax[0], wmax[1]), fmaxf(wmax[2], wmax[3]));
  float e = expf(d - rmax);
  for (int mk = 1; mk <= 32; mk <<= 1) e += __shfl_xor(e, mk, 64);
  if ((jt & 63) == 0) wsum[jt >> 6] = e;
  __syncthreads();
  if (jt == 0) {
    float sum = wsum[0] + wsum[1] + wsum[2] + wsum[3];
    lossrows[i] = rmax + logf(sum) - sel;
  }
}

__global__ __launch_bounds__(256) void sum_kernel(const float* __restrict__ lossrows,
                                                  float* __restrict__ out) {
  int t = threadIdx.x;
  float v = lossrows[t];
  for (int mk = 1; mk <= 32; mk <<= 1) v += __shfl_xor(v, mk, 64);
  __shared__ float wsh[4];
  if ((t & 63) == 0) wsh[t >> 6] = v;
  __syncthreads();
  if (t == 0) out[0] = wsh[0] + wsh[1] + wsh[2] + wsh[3];
}

extern "C" void kernel_launch(void* const* d_in, const int* in_sizes, int n_in,
                              void* d_out, int out_size, void* d_ws, size_t ws_size,
                              hipStream_t stream) {
  (void)in_sizes; (void)n_in; (void)out_size; (void)ws_size;
  const float* zis = (const float*)d_in[0];
  const float* zjs = (const float*)d_in[1];
  const int* speeds = (const int*)d_in[2];
  float* out = (float*)d_out;

  char* ws = (char*)d_ws;
  unsigned short* f1p = (unsigned short*)ws;                       // 512 KB packed A
  unsigned short* f2c = (unsigned short*)(ws + 524288);            // 512 KB
  float* s1 = (float*)(ws + 1048576);                              // 1 KB
  float* s2 = (float*)(ws + 1048576 + 1024);                       // 1 KB
  float* part = (float*)(ws + 1048576 + 2048);                     // 1 MB: [j][chunk][i]
  float* lossrows = (float*)(ws + 1048576 + 2048 + 1048576);       // 1 KB

  prep_kernel<<<512, 256, 0, stream>>>(zis, zjs, f1p, f2c, s1, s2);
  corr_kernel<<<2048, 256, 0, stream>>>(f1p, f2c, part);
  loss_kernel<<<256, 256, 0, stream>>>(part, s1, s2, speeds, lossrows);
  sum_kernel<<<1, 256, 0, stream>>>(lossrows, out);
}

// Round 5
// 292.887 us; speedup vs baseline: 1.7945x; 1.7945x over previous
//
#include <hip/hip_runtime.h>
#include <hip/hip_bf16.h>

#define M_ROWS 256
#define T_LEN  1024
#define NLAG   2048
#define GSTRIDE 2072   // 2048 + 24 tail; word stride 1036 ≡ 12 mod 32 -> copies on disjoint banks

typedef __attribute__((ext_vector_type(8)))  __bf16 bf16x8;
typedef __attribute__((ext_vector_type(16))) float  f32x16;
typedef __attribute__((ext_vector_type(4)))  unsigned int u32x4;

static __device__ __forceinline__ unsigned short f2bf(float f) {
  unsigned int u = __builtin_bit_cast(unsigned int, f);
  u += 0x7FFFu + ((u >> 16) & 1u);   // RNE
  return (unsigned short)(u >> 16);
}

// ---------------- prep: center rows, bf16-ify, std(ddof=1) ----------------
// f1 -> packed fragment layout f1p[kg][row][8]  (kg = k/8), f2 -> row-major
__global__ __launch_bounds__(256) void prep_kernel(
    const float* __restrict__ zis, const float* __restrict__ zjs,
    unsigned short* __restrict__ f1p, unsigned short* __restrict__ f2c,
    float* __restrict__ s1, float* __restrict__ s2) {
  int r = blockIdx.x;  // 0..511
  const float* src = (r < M_ROWS) ? (zis + r * T_LEN) : (zjs + (r - M_ROWS) * T_LEN);
  int t = threadIdx.x;
  float4 v = reinterpret_cast<const float4*>(src)[t];
  float ls = v.x + v.y + v.z + v.w;
  for (int m = 1; m <= 32; m <<= 1) ls += __shfl_xor(ls, m, 64);
  __shared__ float red[4];
  __shared__ float red2[4];
  if ((t & 63) == 0) red[t >> 6] = ls;
  __syncthreads();
  float mean = (red[0] + red[1] + red[2] + red[3]) * (1.0f / 1024.0f);
  float c0 = v.x - mean, c1 = v.y - mean, c2 = v.z - mean, c3 = v.w - mean;
  float ss = c0 * c0 + c1 * c1 + c2 * c2 + c3 * c3;
  for (int m = 1; m <= 32; m <<= 1) ss += __shfl_xor(ss, m, 64);
  if ((t & 63) == 0) red2[t >> 6] = ss;
  __syncthreads();
  float sd = sqrtf((red2[0] + red2[1] + red2[2] + red2[3]) * (1.0f / 1023.0f));
  ushort4 o;
  o.x = f2bf(c0); o.y = f2bf(c1); o.z = f2bf(c2); o.w = f2bf(c3);
  if (r < M_ROWS) {
    if (t == 0) s1[r] = sd;
    reinterpret_cast<ushort4*>(&f1p[(((t >> 1) * 256) + r) * 8 + (t & 1) * 4])[0] = o;
  } else {
    if (t == 0) s2[r - M_ROWS] = sd;
    reinterpret_cast<ushort4*>(&f2c[(r - M_ROWS) * T_LEN + 4 * t])[0] = o;
  }
}

// ---------------- Toeplitz-GEMM correlation + per-row lag-max ----------------
// grid: wg = blk*256 + j ; 4096 wgs, 256 threads = 4 waves, each wave 64 rows x 128 lags
__global__ __launch_bounds__(256) void corr_kernel(
    const unsigned short* __restrict__ f1p,
    const unsigned short* __restrict__ f2c,
    unsigned short* __restrict__ part) {
  __shared__ __align__(16) unsigned short gall[8 * GSTRIDE];  // 33152 B
  __shared__ float red[256];                                  // 1024 B

  int wg = blockIdx.x;
  int j = wg & 255;
  int blk = wg >> 8;       // 0..15
  int tau0 = blk * 128;

  int tid = threadIdx.x;
  int lane = tid & 63;
  int w = tid >> 6;        // wave id: row quarter
  int l5 = lane >> 5;
  int lq = (lane >> 3) & 3;
  int lr = lane & 7;
  int l31 = lane & 31;

  // ---- step A: copy 0 = centered f2 row, zero-padded, +24-elem wrap tail ----
  {
    const unsigned short* f2row = f2c + j * T_LEN;
    if (tid < 128) {
      u32x4 v = *reinterpret_cast<const u32x4*>(f2row + tid * 8);
      *reinterpret_cast<u32x4*>(&gall[tid * 8]) = v;
    } else {
      u32x4 z; z[0] = z[1] = z[2] = z[3] = 0;
      *reinterpret_cast<u32x4*>(&gall[1024 + (tid - 128) * 8]) = z;
      if (tid < 131) {
        u32x4 v = *reinterpret_cast<const u32x4*>(f2row + (tid - 128) * 8);
        *reinterpret_cast<u32x4*>(&gall[2048 + (tid - 128) * 8]) = v;
      }
    }
  }
  __syncthreads();

  // ---- step B: copies r=1..7 via aligned b128 reads + compile-time funnel shift ----
  {
    const unsigned int* g0w = reinterpret_cast<const unsigned int*>(gall);
#pragma unroll
    for (int r = 1; r < 8; ++r) {
      const int kk = (8 - r) >> 1;   // uniform: base bits[2:1]
      for (int c = tid; c < 259; c += 256) {
        int base = (c * 8 - r) & (NLAG - 1);
        int wa = (base >> 1) - kk;   // 4-aligned
        u32x4 W0 = *reinterpret_cast<const u32x4*>(&g0w[wa]);
        u32x4 W1 = *reinterpret_cast<const u32x4*>(&g0w[wa + 4]);
        unsigned int wv[8] = {W0[0], W0[1], W0[2], W0[3], W1[0], W1[1], W1[2], W1[3]};
        u32x4 ow;
        if (r & 1) {
#pragma unroll
          for (int i = 0; i < 4; ++i)
            ow[i] = (wv[kk + i] >> 16) | (wv[kk + i + 1] << 16);
        } else {
#pragma unroll
          for (int i = 0; i < 4; ++i) ow[i] = wv[kk + i];
        }
        *reinterpret_cast<u32x4*>(&gall[r * GSTRIDE + c * 8]) = ow;
      }
    }
  }
  __syncthreads();

  // k-step range for this 128-lag block (tile zero iff m_lo in [1024,1889])
  int kA, kB;
  if (tau0 < 1024) { kA = tau0 >> 5; kB = 32; }
  else             { kA = 0;         kB = ((tau0 - 898) >> 5) + 1; }

  // A base: element ((ks*4 + ksub*2 + l5)*256 + row)*8 ; rows = w*64 .. w*64+63
  const unsigned short* ap = f1p + ((l5 * 256) + w * 64 + l31) * 8 + kA * 8192;
  int bb = lr * GSTRIDE;
  int yb = 8 * l5 - 8 * lq - tau0;  // lag-frag c subtracts c*32

  f32x16 z00, z01, z02, z03, z10, z11, z12, z13;
#pragma unroll
  for (int q = 0; q < 16; ++q) {
    z00[q] = 0.f; z01[q] = 0.f; z02[q] = 0.f; z03[q] = 0.f;
    z10[q] = 0.f; z11[q] = 0.f; z12[q] = 0.f; z13[q] = 0.f;
  }

#pragma unroll 1
  for (int ks = kA; ks < kB; ++ks) {
    bf16x8 a00 = *reinterpret_cast<const bf16x8*>(ap);               // rf0 ksub0
    bf16x8 a10 = *reinterpret_cast<const bf16x8*>(ap + 256);         // rf1 ksub0
    bf16x8 a01 = *reinterpret_cast<const bf16x8*>(ap + 4096);        // rf0 ksub1
    bf16x8 a11 = *reinterpret_cast<const bf16x8*>(ap + 4096 + 256);  // rf1 ksub1
    ap += 8192;
    int ybk = yb + ks * 32;
    int y0 = ybk & (NLAG - 1);
    int y1 = (ybk - 32) & (NLAG - 1);
    int y2 = (ybk - 64) & (NLAG - 1);
    int y3 = (ybk - 96) & (NLAG - 1);
    const unsigned short* bp0 = &gall[bb + y0];
    const unsigned short* bp1 = &gall[bb + y1];
    const unsigned short* bp2 = &gall[bb + y2];
    const unsigned short* bp3 = &gall[bb + y3];
    bf16x8 b00 = *reinterpret_cast<const bf16x8*>(bp0);
    bf16x8 b0k = *reinterpret_cast<const bf16x8*>(bp0 + 16);
    bf16x8 b10 = *reinterpret_cast<const bf16x8*>(bp1);
    bf16x8 b1k = *reinterpret_cast<const bf16x8*>(bp1 + 16);
    bf16x8 b20 = *reinterpret_cast<const bf16x8*>(bp2);
    bf16x8 b2k = *reinterpret_cast<const bf16x8*>(bp2 + 16);
    bf16x8 b30 = *reinterpret_cast<const bf16x8*>(bp3);
    bf16x8 b3k = *reinterpret_cast<const bf16x8*>(bp3 + 16);
    z00 = __builtin_amdgcn_mfma_f32_32x32x16_bf16(a00, b00, z00, 0, 0, 0);
    z10 = __builtin_amdgcn_mfma_f32_32x32x16_bf16(a10, b00, z10, 0, 0, 0);
    z01 = __builtin_amdgcn_mfma_f32_32x32x16_bf16(a00, b10, z01, 0, 0, 0);
    z11 = __builtin_amdgcn_mfma_f32_32x32x16_bf16(a10, b10, z11, 0, 0, 0);
    z02 = __builtin_amdgcn_mfma_f32_32x32x16_bf16(a00, b20, z02, 0, 0, 0);
    z12 = __builtin_amdgcn_mfma_f32_32x32x16_bf16(a10, b20, z12, 0, 0, 0);
    z03 = __builtin_amdgcn_mfma_f32_32x32x16_bf16(a00, b30, z03, 0, 0, 0);
    z13 = __builtin_amdgcn_mfma_f32_32x32x16_bf16(a10, b30, z13, 0, 0, 0);
    z00 = __builtin_amdgcn_mfma_f32_32x32x16_bf16(a01, b0k, z00, 0, 0, 0);
    z10 = __builtin_amdgcn_mfma_f32_32x32x16_bf16(a11, b0k, z10, 0, 0, 0);
    z01 = __builtin_amdgcn_mfma_f32_32x32x16_bf16(a01, b1k, z01, 0, 0, 0);
    z11 = __builtin_amdgcn_mfma_f32_32x32x16_bf16(a11, b1k, z11, 0, 0, 0);
    z02 = __builtin_amdgcn_mfma_f32_32x32x16_bf16(a01, b2k, z02, 0, 0, 0);
    z12 = __builtin_amdgcn_mfma_f32_32x32x16_bf16(a11, b2k, z12, 0, 0, 0);
    z03 = __builtin_amdgcn_mfma_f32_32x32x16_bf16(a01, b3k, z03, 0, 0, 0);
    z13 = __builtin_amdgcn_mfma_f32_32x32x16_bf16(a11, b3k, z13, 0, 0, 0);
  }

  // per-row max over the 128 lags of this block, then cross-lane over 32 cols
#pragma unroll
  for (int rf = 0; rf < 2; ++rf) {
#pragma unroll
    for (int q = 0; q < 16; ++q) {
      float v;
      if (rf == 0) v = fmaxf(fmaxf(z00[q], z01[q]), fmaxf(z02[q], z03[q]));
      else         v = fmaxf(fmaxf(z10[q], z11[q]), fmaxf(z12[q], z13[q]));
      v = fmaxf(v, __shfl_xor(v, 1, 64));
      v = fmaxf(v, __shfl_xor(v, 2, 64));
      v = fmaxf(v, __shfl_xor(v, 4, 64));
      v = fmaxf(v, __shfl_xor(v, 8, 64));
      v = fmaxf(v, __shfl_xor(v, 16, 64));
      if (l31 == 0) red[w * 64 + rf * 32 + (q & 3) + 8 * (q >> 2) + 4 * l5] = v;
    }
  }
  __syncthreads();
  // part[i][blk][j] (bf16) for coalesced loss reads
  part[(tid * 16 + blk) * 256 + j] = f2bf(red[tid]);
}

// ---------------- per-row CE: dist, logsumexp, pick target ----------------
__global__ __launch_bounds__(256) void loss_kernel(
    const unsigned short* __restrict__ part, const float* __restrict__ s1,
    const float* __restrict__ s2, const int* __restrict__ speeds,
    float* __restrict__ lossrows) {
  int i = blockIdx.x;
  int jt = threadIdx.x;
  unsigned short um = part[(i * 16 + 0) * 256 + jt];
  float m = __builtin_bit_cast(float, ((unsigned int)um) << 16);
#pragma unroll
  for (int b = 1; b < 16; ++b) {
    unsigned short ub = part[(i * 16 + b) * 256 + jt];
    m = fmaxf(m, __builtin_bit_cast(float, ((unsigned int)ub) << 16));
  }
  float p = s1[i] * s2[jt];
  p = (p == 0.0f) ? 1.0f : p;
  float d = m / (p * 1023.0f);

  float t = d;
  for (int mk = 1; mk <= 32; mk <<= 1) t = fmaxf(t, __shfl_xor(t, mk, 64));
  __shared__ float wmax[4], wsum[4], sel;
  if ((jt & 63) == 0) wmax[jt >> 6] = t;
  if (jt == speeds[i]) sel = d;
  __syncthreads();
  float rmax = fmaxf(fmaxf(wmax[0], wmax[1]), fmaxf(wmax[2], wmax[3]));
  float e = expf(d - rmax);
  for (int mk = 1; mk <= 32; mk <<= 1) e += __shfl_xor(e, mk, 64);
  if ((jt & 63) == 0) wsum[jt >> 6] = e;
  __syncthreads();
  if (jt == 0) {
    float sum = wsum[0] + wsum[1] + wsum[2] + wsum[3];
    lossrows[i] = rmax + logf(sum) - sel;
  }
}

__global__ __launch_bounds__(256) void sum_kernel(const float* __restrict__ lossrows,
                                                  float* __restrict__ out) {
  int t = threadIdx.x;
  float v = lossrows[t];
  for (int mk = 1; mk <= 32; mk <<= 1) v += __shfl_xor(v, mk, 64);
  __shared__ float wsh[4];
  if ((t & 63) == 0) wsh[t >> 6] = v;
  __syncthreads();
  if (t == 0) out[0] = wsh[0] + wsh[1] + wsh[2] + wsh[3];
}

extern "C" void kernel_launch(void* const* d_in, const int* in_sizes, int n_in,
                              void* d_out, int out_size, void* d_ws, size_t ws_size,
                              hipStream_t stream) {
  (void)in_sizes; (void)n_in; (void)out_size; (void)ws_size;
  const float* zis = (const float*)d_in[0];
  const float* zjs = (const float*)d_in[1];
  const int* speeds = (const int*)d_in[2];
  float* out = (float*)d_out;

  char* ws = (char*)d_ws;
  unsigned short* f1p = (unsigned short*)ws;                       // 512 KB packed A
  unsigned short* f2c = (unsigned short*)(ws + 524288);            // 512 KB
  float* s1 = (float*)(ws + 1048576);                              // 1 KB
  float* s2 = (float*)(ws + 1048576 + 1024);                       // 1 KB
  unsigned short* part = (unsigned short*)(ws + 1048576 + 2048);   // 2 MB bf16 [i][blk][j]
  float* lossrows = (float*)(ws + 1048576 + 2048 + 2097152);       // 1 KB

  prep_kernel<<<512, 256, 0, stream>>>(zis, zjs, f1p, f2c, s1, s2);
  corr_kernel<<<4096, 256, 0, stream>>>(f1p, f2c, part);
  loss_kernel<<<256, 256, 0, stream>>>(part, s1, s2, speeds, lossrows);
  sum_kernel<<<1, 256, 0, stream>>>(lossrows, out);
}

// Round 6
// 172.272 us; speedup vs baseline: 3.0510x; 1.7001x over previous
//
#include <hip/hip_runtime.h>
#include <hip/hip_bf16.h>

#define M_ROWS 256
#define T_LEN  1024
#define NLAG   2048
#define GSTRIDE 2072   // 2048 + 24 tail; word stride 1036 ≡ 12 mod 32 -> copies on disjoint banks

typedef __attribute__((ext_vector_type(8)))  __bf16 bf16x8;
typedef __attribute__((ext_vector_type(16))) float  f32x16;
typedef __attribute__((ext_vector_type(4)))  unsigned int u32x4;

static __device__ __forceinline__ unsigned short f2bf(float f) {
  unsigned int u = __builtin_bit_cast(unsigned int, f);
  u += 0x7FFFu + ((u >> 16) & 1u);   // RNE
  return (unsigned short)(u >> 16);
}

// ---------------- prep: center rows, bf16-ify, std(ddof=1) ----------------
// f1 -> packed fragment layout f1p[kg][row][8]  (kg = k/8), f2 -> row-major
__global__ __launch_bounds__(256) void prep_kernel(
    const float* __restrict__ zis, const float* __restrict__ zjs,
    unsigned short* __restrict__ f1p, unsigned short* __restrict__ f2c,
    float* __restrict__ s1, float* __restrict__ s2) {
  int r = blockIdx.x;  // 0..511
  const float* src = (r < M_ROWS) ? (zis + r * T_LEN) : (zjs + (r - M_ROWS) * T_LEN);
  int t = threadIdx.x;
  float4 v = reinterpret_cast<const float4*>(src)[t];
  float ls = v.x + v.y + v.z + v.w;
  for (int m = 1; m <= 32; m <<= 1) ls += __shfl_xor(ls, m, 64);
  __shared__ float red[4];
  __shared__ float red2[4];
  if ((t & 63) == 0) red[t >> 6] = ls;
  __syncthreads();
  float mean = (red[0] + red[1] + red[2] + red[3]) * (1.0f / 1024.0f);
  float c0 = v.x - mean, c1 = v.y - mean, c2 = v.z - mean, c3 = v.w - mean;
  float ss = c0 * c0 + c1 * c1 + c2 * c2 + c3 * c3;
  for (int m = 1; m <= 32; m <<= 1) ss += __shfl_xor(ss, m, 64);
  if ((t & 63) == 0) red2[t >> 6] = ss;
  __syncthreads();
  float sd = sqrtf((red2[0] + red2[1] + red2[2] + red2[3]) * (1.0f / 1023.0f));
  ushort4 o;
  o.x = f2bf(c0); o.y = f2bf(c1); o.z = f2bf(c2); o.w = f2bf(c3);
  if (r < M_ROWS) {
    if (t == 0) s1[r] = sd;
    reinterpret_cast<ushort4*>(&f1p[(((t >> 1) * 256) + r) * 8 + (t & 1) * 4])[0] = o;
  } else {
    if (t == 0) s2[r - M_ROWS] = sd;
    reinterpret_cast<ushort4*>(&f2c[(r - M_ROWS) * T_LEN + 4 * t])[0] = o;
  }
}

#define LOADA(A0, A1, A2, A3)                                    \
  {                                                              \
    A0 = *reinterpret_cast<const bf16x8*>(ap);                   \
    A1 = *reinterpret_cast<const bf16x8*>(ap + 256);             \
    A2 = *reinterpret_cast<const bf16x8*>(ap + 4096);            \
    A3 = *reinterpret_cast<const bf16x8*>(ap + 4096 + 256);      \
    ap += 8192;                                                  \
  }

// one k-step: B loaded in two ksub phases (4 live B regs sets of 4), 16 MFMA
#define PHASES(A0, A1, A2, A3, KS)                                                 \
  {                                                                                \
    int ybk = yb + (KS) * 32;                                                      \
    const unsigned short* bq0 = &gall[bb + (ybk & (NLAG - 1))];                    \
    const unsigned short* bq1 = &gall[bb + ((ybk - 32) & (NLAG - 1))];             \
    const unsigned short* bq2 = &gall[bb + ((ybk - 64) & (NLAG - 1))];             \
    const unsigned short* bq3 = &gall[bb + ((ybk - 96) & (NLAG - 1))];             \
    bf16x8 b0 = *reinterpret_cast<const bf16x8*>(bq0);                             \
    bf16x8 b1 = *reinterpret_cast<const bf16x8*>(bq1);                             \
    bf16x8 b2 = *reinterpret_cast<const bf16x8*>(bq2);                             \
    bf16x8 b3 = *reinterpret_cast<const bf16x8*>(bq3);                             \
    z00 = __builtin_amdgcn_mfma_f32_32x32x16_bf16(A0, b0, z00, 0, 0, 0);           \
    z10 = __builtin_amdgcn_mfma_f32_32x32x16_bf16(A1, b0, z10, 0, 0, 0);           \
    z01 = __builtin_amdgcn_mfma_f32_32x32x16_bf16(A0, b1, z01, 0, 0, 0);           \
    z11 = __builtin_amdgcn_mfma_f32_32x32x16_bf16(A1, b1, z11, 0, 0, 0);           \
    z02 = __builtin_amdgcn_mfma_f32_32x32x16_bf16(A0, b2, z02, 0, 0, 0);           \
    z12 = __builtin_amdgcn_mfma_f32_32x32x16_bf16(A1, b2, z12, 0, 0, 0);           \
    z03 = __builtin_amdgcn_mfma_f32_32x32x16_bf16(A0, b3, z03, 0, 0, 0);           \
    z13 = __builtin_amdgcn_mfma_f32_32x32x16_bf16(A1, b3, z13, 0, 0, 0);           \
    b0 = *reinterpret_cast<const bf16x8*>(bq0 + 16);                               \
    b1 = *reinterpret_cast<const bf16x8*>(bq1 + 16);                               \
    b2 = *reinterpret_cast<const bf16x8*>(bq2 + 16);                               \
    b3 = *reinterpret_cast<const bf16x8*>(bq3 + 16);                               \
    z00 = __builtin_amdgcn_mfma_f32_32x32x16_bf16(A2, b0, z00, 0, 0, 0);           \
    z10 = __builtin_amdgcn_mfma_f32_32x32x16_bf16(A3, b0, z10, 0, 0, 0);           \
    z01 = __builtin_amdgcn_mfma_f32_32x32x16_bf16(A2, b1, z01, 0, 0, 0);           \
    z11 = __builtin_amdgcn_mfma_f32_32x32x16_bf16(A3, b1, z11, 0, 0, 0);           \
    z02 = __builtin_amdgcn_mfma_f32_32x32x16_bf16(A2, b2, z02, 0, 0, 0);           \
    z12 = __builtin_amdgcn_mfma_f32_32x32x16_bf16(A3, b2, z12, 0, 0, 0);           \
    z03 = __builtin_amdgcn_mfma_f32_32x32x16_bf16(A2, b3, z03, 0, 0, 0);           \
    z13 = __builtin_amdgcn_mfma_f32_32x32x16_bf16(A3, b3, z13, 0, 0, 0);           \
  }

// ---------------- Toeplitz-GEMM correlation + per-row lag-max ----------------
// grid: wg = blk*256 + j ; 4096 wgs, 256 threads = 4 waves, each wave 64 rows x 128 lags
__global__ __launch_bounds__(256, 2) void corr_kernel(
    const unsigned short* __restrict__ f1p,
    const unsigned short* __restrict__ f2c,
    unsigned short* __restrict__ part) {
  __shared__ __align__(16) unsigned short gall[8 * GSTRIDE];  // 33152 B
  __shared__ float red[256];                                  // 1024 B

  int wg = blockIdx.x;
  int j = wg & 255;
  int blk = wg >> 8;       // 0..15
  int tau0 = blk * 128;

  int tid = threadIdx.x;
  int lane = tid & 63;
  int w = tid >> 6;        // wave id: row quarter
  int l5 = lane >> 5;
  int lq = (lane >> 3) & 3;
  int lr = lane & 7;
  int l31 = lane & 31;

  // ---- step A: copy 0 = centered f2 row, zero-padded, +24-elem wrap tail ----
  {
    const unsigned short* f2row = f2c + j * T_LEN;
    if (tid < 128) {
      u32x4 v = *reinterpret_cast<const u32x4*>(f2row + tid * 8);
      *reinterpret_cast<u32x4*>(&gall[tid * 8]) = v;
    } else {
      u32x4 z; z[0] = z[1] = z[2] = z[3] = 0;
      *reinterpret_cast<u32x4*>(&gall[1024 + (tid - 128) * 8]) = z;
      if (tid < 131) {
        u32x4 v = *reinterpret_cast<const u32x4*>(f2row + (tid - 128) * 8);
        *reinterpret_cast<u32x4*>(&gall[2048 + (tid - 128) * 8]) = v;
      }
    }
  }
  __syncthreads();

  // ---- step B: copies r=1..7 via aligned b128 reads + compile-time funnel shift ----
  {
    const unsigned int* g0w = reinterpret_cast<const unsigned int*>(gall);
#pragma unroll
    for (int r = 1; r < 8; ++r) {
      const int kk = (8 - r) >> 1;   // uniform: base bits[2:1]
      for (int c = tid; c < 259; c += 256) {
        int base = (c * 8 - r) & (NLAG - 1);
        int wa = (base >> 1) - kk;   // 4-aligned
        u32x4 W0 = *reinterpret_cast<const u32x4*>(&g0w[wa]);
        u32x4 W1 = *reinterpret_cast<const u32x4*>(&g0w[wa + 4]);
        unsigned int wv[8] = {W0[0], W0[1], W0[2], W0[3], W1[0], W1[1], W1[2], W1[3]};
        u32x4 ow;
        if (r & 1) {
#pragma unroll
          for (int i = 0; i < 4; ++i)
            ow[i] = (wv[kk + i] >> 16) | (wv[kk + i + 1] << 16);
        } else {
#pragma unroll
          for (int i = 0; i < 4; ++i) ow[i] = wv[kk + i];
        }
        *reinterpret_cast<u32x4*>(&gall[r * GSTRIDE + c * 8]) = ow;
      }
    }
  }
  __syncthreads();

  // k-step range for this 128-lag block (always even count, >= 4)
  int kA, kB;
  if (tau0 < 1024) { kA = tau0 >> 5; kB = 32; }
  else             { kA = 0;         kB = ((tau0 - 898) >> 5) + 1; }

  // A base: element ((ks*4 + ksub*2 + l5)*256 + row)*8 ; rows = w*64 .. w*64+63
  const unsigned short* ap = f1p + ((l5 * 256) + w * 64 + l31) * 8 + kA * 8192;
  int bb = lr * GSTRIDE;
  int yb = 8 * l5 - 8 * lq - tau0;  // lag-frag c subtracts c*32

  f32x16 z00, z01, z02, z03, z10, z11, z12, z13;
#pragma unroll
  for (int q = 0; q < 16; ++q) {
    z00[q] = 0.f; z01[q] = 0.f; z02[q] = 0.f; z03[q] = 0.f;
    z10[q] = 0.f; z11[q] = 0.f; z12[q] = 0.f; z13[q] = 0.f;
  }

  // software pipeline: A double-buffered (X/Y), B loaded per ksub phase
  bf16x8 xa0, xa1, xa2, xa3, ya0, ya1, ya2, ya3;
  LOADA(xa0, xa1, xa2, xa3);
  int ks = kA;
#pragma unroll 1
  for (; ks + 2 < kB; ks += 2) {
    LOADA(ya0, ya1, ya2, ya3);
    PHASES(xa0, xa1, xa2, xa3, ks);
    LOADA(xa0, xa1, xa2, xa3);
    PHASES(ya0, ya1, ya2, ya3, ks + 1);
  }
  LOADA(ya0, ya1, ya2, ya3);
  PHASES(xa0, xa1, xa2, xa3, ks);
  PHASES(ya0, ya1, ya2, ya3, ks + 1);

  // per-row max over the 128 lags of this block, then cross-lane over 32 cols
#pragma unroll
  for (int rf = 0; rf < 2; ++rf) {
#pragma unroll
    for (int q = 0; q < 16; ++q) {
      float v;
      if (rf == 0) v = fmaxf(fmaxf(z00[q], z01[q]), fmaxf(z02[q], z03[q]));
      else         v = fmaxf(fmaxf(z10[q], z11[q]), fmaxf(z12[q], z13[q]));
      v = fmaxf(v, __shfl_xor(v, 1, 64));
      v = fmaxf(v, __shfl_xor(v, 2, 64));
      v = fmaxf(v, __shfl_xor(v, 4, 64));
      v = fmaxf(v, __shfl_xor(v, 8, 64));
      v = fmaxf(v, __shfl_xor(v, 16, 64));
      if (l31 == 0) red[w * 64 + rf * 32 + (q & 3) + 8 * (q >> 2) + 4 * l5] = v;
    }
  }
  __syncthreads();
  // part[i][blk][j] (bf16) for coalesced loss reads
  part[(tid * 16 + blk) * 256 + j] = f2bf(red[tid]);
}

// ---------------- per-row CE: dist, logsumexp, pick target ----------------
__global__ __launch_bounds__(256) void loss_kernel(
    const unsigned short* __restrict__ part, const float* __restrict__ s1,
    const float* __restrict__ s2, const int* __restrict__ speeds,
    float* __restrict__ lossrows) {
  int i = blockIdx.x;
  int jt = threadIdx.x;
  unsigned short um = part[(i * 16 + 0) * 256 + jt];
  float m = __builtin_bit_cast(float, ((unsigned int)um) << 16);
#pragma unroll
  for (int b = 1; b < 16; ++b) {
    unsigned short ub = part[(i * 16 + b) * 256 + jt];
    m = fmaxf(m, __builtin_bit_cast(float, ((unsigned int)ub) << 16));
  }
  float p = s1[i] * s2[jt];
  p = (p == 0.0f) ? 1.0f : p;
  float d = m / (p * 1023.0f);

  float t = d;
  for (int mk = 1; mk <= 32; mk <<= 1) t = fmaxf(t, __shfl_xor(t, mk, 64));
  __shared__ float wmax[4], wsum[4], sel;
  if ((jt & 63) == 0) wmax[jt >> 6] = t;
  if (jt == speeds[i]) sel = d;
  __syncthreads();
  float rmax = fmaxf(fmaxf(wmax[0], wmax[1]), fmaxf(wmax[2], wmax[3]));
  float e = expf(d - rmax);
  for (int mk = 1; mk <= 32; mk <<= 1) e += __shfl_xor(e, mk, 64);
  if ((jt & 63) == 0) wsum[jt >> 6] = e;
  __syncthreads();
  if (jt == 0) {
    float sum = wsum[0] + wsum[1] + wsum[2] + wsum[3];
    lossrows[i] = rmax + logf(sum) - sel;
  }
}

__global__ __launch_bounds__(256) void sum_kernel(const float* __restrict__ lossrows,
                                                  float* __restrict__ out) {
  int t = threadIdx.x;
  float v = lossrows[t];
  for (int mk = 1; mk <= 32; mk <<= 1) v += __shfl_xor(v, mk, 64);
  __shared__ float wsh[4];
  if ((t & 63) == 0) wsh[t >> 6] = v;
  __syncthreads();
  if (t == 0) out[0] = wsh[0] + wsh[1] + wsh[2] + wsh[3];
}

extern "C" void kernel_launch(void* const* d_in, const int* in_sizes, int n_in,
                              void* d_out, int out_size, void* d_ws, size_t ws_size,
                              hipStream_t stream) {
  (void)in_sizes; (void)n_in; (void)out_size; (void)ws_size;
  const float* zis = (const float*)d_in[0];
  const float* zjs = (const float*)d_in[1];
  const int* speeds = (const int*)d_in[2];
  float* out = (float*)d_out;

  char* ws = (char*)d_ws;
  unsigned short* f1p = (unsigned short*)ws;                       // 512 KB packed A
  unsigned short* f2c = (unsigned short*)(ws + 524288);            // 512 KB
  float* s1 = (float*)(ws + 1048576);                              // 1 KB
  float* s2 = (float*)(ws + 1048576 + 1024);                       // 1 KB
  unsigned short* part = (unsigned short*)(ws + 1048576 + 2048);   // 2 MB bf16 [i][blk][j]
  float* lossrows = (float*)(ws + 1048576 + 2048 + 2097152);       // 1 KB

  prep_kernel<<<512, 256, 0, stream>>>(zis, zjs, f1p, f2c, s1, s2);
  corr_kernel<<<4096, 256, 0, stream>>>(f1p, f2c, part);
  loss_kernel<<<256, 256, 0, stream>>>(part, s1, s2, speeds, lossrows);
  sum_kernel<<<1, 256, 0, stream>>>(lossrows, out);
}

// Round 7
// 77.301 us; speedup vs baseline: 6.7994x; 2.2286x over previous
//
#include <hip/hip_runtime.h>
#include <hip/hip_bf16.h>

#define M_ROWS 256
#define T_LEN  1024
#define NLAG   2048
#define GSTB   2096   // bytes per shifted fp8 copy in LDS; 524 words == 12 mod 32 -> uniform banks
#define NCOPY  16
#define GPZW   520    // u32 words per padded fp8 row in global (2080 B: row|zeros|wrap-tail)

typedef __attribute__((ext_vector_type(4)))  unsigned int u32x4;
typedef __attribute__((ext_vector_type(8)))  int          i32x8;
typedef __attribute__((ext_vector_type(16))) float        f32x16;

static __device__ __forceinline__ unsigned short f2bf(float f) {
  unsigned int u = __builtin_bit_cast(unsigned int, f);
  u += 0x7FFFu + ((u >> 16) & 1u);   // RNE
  return (unsigned short)(u >> 16);
}

// ---------------- prep: center rows, fp8-ify, std(ddof=1) ----------------
// f1 -> packed fragment bytes f1p8[[kg][h][row][32B]]; f2 -> padded fp8 rows gpz8[256][2080B]
__global__ __launch_bounds__(256) void prep_kernel(
    const float* __restrict__ zis, const float* __restrict__ zjs,
    unsigned int* __restrict__ f1p8, unsigned int* __restrict__ gpz8,
    float* __restrict__ s1, float* __restrict__ s2) {
  int r = blockIdx.x;  // 0..511
  const float* src = (r < M_ROWS) ? (zis + r * T_LEN) : (zjs + (r - M_ROWS) * T_LEN);
  int t = threadIdx.x;
  float4 v = reinterpret_cast<const float4*>(src)[t];
  float ls = v.x + v.y + v.z + v.w;
  for (int m = 1; m <= 32; m <<= 1) ls += __shfl_xor(ls, m, 64);
  __shared__ float red[4];
  __shared__ float red2[4];
  if ((t & 63) == 0) red[t >> 6] = ls;
  __syncthreads();
  float mean = (red[0] + red[1] + red[2] + red[3]) * (1.0f / 1024.0f);
  float c0 = v.x - mean, c1 = v.y - mean, c2 = v.z - mean, c3 = v.w - mean;
  float ss = c0 * c0 + c1 * c1 + c2 * c2 + c3 * c3;
  for (int m = 1; m <= 32; m <<= 1) ss += __shfl_xor(ss, m, 64);
  if ((t & 63) == 0) red2[t >> 6] = ss;
  __syncthreads();
  float sd = sqrtf((red2[0] + red2[1] + red2[2] + red2[3]) * (1.0f / 1023.0f));

  unsigned int w = (unsigned int)__builtin_amdgcn_cvt_pk_fp8_f32(c0, c1, 0, false);
  w = (unsigned int)__builtin_amdgcn_cvt_pk_fp8_f32(c2, c3, (int)w, true);

  if (r < M_ROWS) {
    if (t == 0) s1[r] = sd;
    // elems 4t..4t+3: kg = t>>4, h = (t>>3)&1, word-in-block = t&7
    f1p8[((((t >> 4) * 2 + ((t >> 3) & 1)) * 256 + r) << 3) + (t & 7)] = w;
  } else {
    int rb = r - M_ROWS;
    if (t == 0) s2[rb] = sd;
    gpz8[rb * GPZW + t] = w;              // row bytes 0..1023
    gpz8[rb * GPZW + 256 + t] = 0u;       // zero pad 1024..2047
    if (t < 8) gpz8[rb * GPZW + 512 + t] = w;  // wrap tail 2048..2079 = row[0..31]
  }
}

#define MK8(LO, HI) \
  (i32x8){(int)(LO)[0], (int)(LO)[1], (int)(LO)[2], (int)(LO)[3], \
          (int)(HI)[0], (int)(HI)[1], (int)(HI)[2], (int)(HI)[3]}

#define LOADF(F0L, F0H, F1L, F1H)            \
  {                                          \
    F0L = *(const u32x4*)(fp);               \
    F0H = *(const u32x4*)(fp + 4);           \
    F1L = *(const u32x4*)(fp + 256);         \
    F1H = *(const u32x4*)(fp + 260);         \
    fp += 4096;                              \
  }

// one K=64 step: G (lags) from LDS just-in-time, F (rows) from pipelined regs; 4 scaled MFMA
#define STEP(F0L, F0H, F1L, F1H, KS)                                                     \
  {                                                                                      \
    int x0 = (((KS) << 6) + cst0) & (NLAG - 1);                                          \
    int x1 = (((KS) << 6) + cst1) & (NLAG - 1);                                          \
    u32x4 g0l = *(const u32x4*)(gbase + x0);                                             \
    u32x4 g0h = *(const u32x4*)(gbase + x0 + 16);                                        \
    u32x4 g1l = *(const u32x4*)(gbase + x1);                                             \
    u32x4 g1h = *(const u32x4*)(gbase + x1 + 16);                                        \
    i32x8 G0 = MK8(g0l, g0h);                                                            \
    i32x8 G1 = MK8(g1l, g1h);                                                            \
    i32x8 F0 = MK8(F0L, F0H);                                                            \
    i32x8 F1 = MK8(F1L, F1H);                                                            \
    z00 = __builtin_amdgcn_mfma_scale_f32_32x32x64_f8f6f4(G0, F0, z00, 0, 0, 0, 127, 0, 127); \
    z01 = __builtin_amdgcn_mfma_scale_f32_32x32x64_f8f6f4(G0, F1, z01, 0, 0, 0, 127, 0, 127); \
    z10 = __builtin_amdgcn_mfma_scale_f32_32x32x64_f8f6f4(G1, F0, z10, 0, 0, 0, 127, 0, 127); \
    z11 = __builtin_amdgcn_mfma_scale_f32_32x32x64_f8f6f4(G1, F1, z11, 0, 0, 0, 127, 0, 127); \
  }

// ---------------- Toeplitz-GEMM correlation (MX-fp8, swapped operands) ----------------
// grid: wg = blk*256 + j ; 4096 wgs, 512 threads = 8 waves.
// wave w: rows (w&3)*64 .. +63 (as MFMA-B), lags tau0 + (w>>2)*64 .. +63 (as MFMA-A).
__global__ __launch_bounds__(512, 4) void corr_kernel(
    const unsigned int* __restrict__ f1p8,
    const unsigned int* __restrict__ gpz8,
    unsigned short* __restrict__ part) {
  __shared__ __align__(16) unsigned char ldsB[NCOPY * GSTB];  // 33536 B
  __shared__ float red[2][256];

  int wg = blockIdx.x;
  int j = wg & 255;
  int blk = wg >> 8;        // 0..15
  int tau0 = blk << 7;

  int tid = threadIdx.x;
  int lane = tid & 63;
  int w = tid >> 6;
  int rw = w & 3;           // row quarter
  int lh = w >> 2;          // lag half (64-lag granule)
  int l5 = lane >> 5;
  int l31 = lane & 31;

  // ---- build 16 byte-shifted fp8 copies: copy r byte x = gp[(x - r) mod 2048] ----
  {
    const unsigned int* gj = gpz8 + j * GPZW;
#pragma unroll
    for (int m = 0; m < 5; ++m) {
      int ch = m * 512 + tid;
      if (ch < 2096) {
        int rr = ch & 15, cc = ch >> 4;
        int base = ((cc << 4) - rr) & (NLAG - 1);
        int wb = base >> 2;
        int sh = (base & 3) << 3;
        unsigned int w0 = gj[wb], w1 = gj[wb + 1], w2 = gj[wb + 2], w3 = gj[wb + 3], w4 = gj[wb + 4];
        u32x4 o;
        if (sh) {
          o[0] = (w0 >> sh) | (w1 << (32 - sh));
          o[1] = (w1 >> sh) | (w2 << (32 - sh));
          o[2] = (w2 >> sh) | (w3 << (32 - sh));
          o[3] = (w3 >> sh) | (w4 << (32 - sh));
        } else {
          o[0] = w0; o[1] = w1; o[2] = w2; o[3] = w3;
        }
        *(u32x4*)(ldsB + ch * 16) = o;
      }
    }
  }
  __syncthreads();

  // k64-step range for this 128-lag block
  int kA, kB;
  if (tau0 < 1024) { kA = tau0 >> 6; kB = 16; }
  else             { kA = 0;         kB = ((tau0 - 898) >> 6) + 1; }
  // kB - kA is even and >= 2

  // F (rows, MFMA-B operand): u32 index ((ks*2 + l5)*256 + row)*8
  const unsigned int* fp = f1p8 + ((((kA * 2 + l5) * 256) + rw * 64 + l31) << 3);
  // G (lags, MFMA-A operand): copy rB = lag mod 16, 16B-aligned offset within copy
  int rB = l31 & 15;
  const unsigned char* gbase = ldsB + rB * GSTB;
  int cst0 = 32 * l5 - tau0 - 32 * (2 * lh) - ((l31 >> 4) << 4);
  int cst1 = cst0 - 32;

  f32x16 z00, z01, z10, z11;  // z[lag-frag][row-frag]
#pragma unroll
  for (int q = 0; q < 16; ++q) { z00[q] = 0.f; z01[q] = 0.f; z10[q] = 0.f; z11[q] = 0.f; }

  u32x4 xf0l, xf0h, xf1l, xf1h, yf0l, yf0h, yf1l, yf1h;
  LOADF(xf0l, xf0h, xf1l, xf1h);
  int ks = kA;
#pragma unroll 1
  for (; ks + 2 < kB; ks += 2) {
    LOADF(yf0l, yf0h, yf1l, yf1h);
    STEP(xf0l, xf0h, xf1l, xf1h, ks);
    LOADF(xf0l, xf0h, xf1l, xf1h);
    STEP(yf0l, yf0h, yf1l, yf1h, ks + 1);
  }
  LOADF(yf0l, yf0h, yf1l, yf1h);
  STEP(xf0l, xf0h, xf1l, xf1h, ks);
  STEP(yf0l, yf0h, yf1l, yf1h, ks + 1);

  // ---- per-row max: lags are lane-local (swap trick) -> in-register fold + 1 shuffle ----
  float a0 = fmaxf(z00[0], z10[0]);
  float a1 = fmaxf(z01[0], z11[0]);
#pragma unroll
  for (int q = 1; q < 16; ++q) {
    a0 = fmaxf(a0, fmaxf(z00[q], z10[q]));
    a1 = fmaxf(a1, fmaxf(z01[q], z11[q]));
  }
  a0 = fmaxf(a0, __shfl_xor(a0, 32, 64));
  a1 = fmaxf(a1, __shfl_xor(a1, 32, 64));
  if (l5 == 0) {
    red[lh][rw * 64 + l31] = a0;        // rows rw*64 + 0..31
    red[lh][rw * 64 + 32 + l31] = a1;   // rows rw*64 + 32..63
  }
  __syncthreads();
  if (tid < 256)
    part[(tid * 16 + blk) * 256 + j] = f2bf(fmaxf(red[0][tid], red[1][tid]));
}

// ---------------- per-row CE: dist, logsumexp, pick target ----------------
__global__ __launch_bounds__(256) void loss_kernel(
    const unsigned short* __restrict__ part, const float* __restrict__ s1,
    const float* __restrict__ s2, const int* __restrict__ speeds,
    float* __restrict__ lossrows) {
  int i = blockIdx.x;
  int jt = threadIdx.x;
  unsigned short um = part[(i * 16 + 0) * 256 + jt];
  float m = __builtin_bit_cast(float, ((unsigned int)um) << 16);
#pragma unroll
  for (int b = 1; b < 16; ++b) {
    unsigned short ub = part[(i * 16 + b) * 256 + jt];
    m = fmaxf(m, __builtin_bit_cast(float, ((unsigned int)ub) << 16));
  }
  float p = s1[i] * s2[jt];
  p = (p == 0.0f) ? 1.0f : p;
  float d = m / (p * 1023.0f);

  float t = d;
  for (int mk = 1; mk <= 32; mk <<= 1) t = fmaxf(t, __shfl_xor(t, mk, 64));
  __shared__ float wmax[4], wsum[4], sel;
  if ((jt & 63) == 0) wmax[jt >> 6] = t;
  if (jt == speeds[i]) sel = d;
  __syncthreads();
  float rmax = fmaxf(fmaxf(wmax[0], wmax[1]), fmaxf(wmax[2], wmax[3]));
  float e = expf(d - rmax);
  for (int mk = 1; mk <= 32; mk <<= 1) e += __shfl_xor(e, mk, 64);
  if ((jt & 63) == 0) wsum[jt >> 6] = e;
  __syncthreads();
  if (jt == 0) {
    float sum = wsum[0] + wsum[1] + wsum[2] + wsum[3];
    lossrows[i] = rmax + logf(sum) - sel;
  }
}

__global__ __launch_bounds__(256) void sum_kernel(const float* __restrict__ lossrows,
                                                  float* __restrict__ out) {
  int t = threadIdx.x;
  float v = lossrows[t];
  for (int mk = 1; mk <= 32; mk <<= 1) v += __shfl_xor(v, mk, 64);
  __shared__ float wsh[4];
  if ((t & 63) == 0) wsh[t >> 6] = v;
  __syncthreads();
  if (t == 0) out[0] = wsh[0] + wsh[1] + wsh[2] + wsh[3];
}

extern "C" void kernel_launch(void* const* d_in, const int* in_sizes, int n_in,
                              void* d_out, int out_size, void* d_ws, size_t ws_size,
                              hipStream_t stream) {
  (void)in_sizes; (void)n_in; (void)out_size; (void)ws_size;
  const float* zis = (const float*)d_in[0];
  const float* zjs = (const float*)d_in[1];
  const int* speeds = (const int*)d_in[2];
  float* out = (float*)d_out;

  char* ws = (char*)d_ws;
  unsigned int* f1p8 = (unsigned int*)ws;                          // 256 KB packed fp8 A
  unsigned int* gpz8 = (unsigned int*)(ws + 262144);               // 520 KB padded fp8 rows
  float* s1 = (float*)(ws + 794624);                               // 1 KB
  float* s2 = (float*)(ws + 795648);                               // 1 KB
  unsigned short* part = (unsigned short*)(ws + 796672);           // 2 MB bf16 [i][blk][j]
  float* lossrows = (float*)(ws + 796672 + 2097152);               // 1 KB

  prep_kernel<<<512, 256, 0, stream>>>(zis, zjs, f1p8, gpz8, s1, s2);
  corr_kernel<<<4096, 512, 0, stream>>>(f1p8, gpz8, part);
  loss_kernel<<<256, 256, 0, stream>>>(part, s1, s2, speeds, lossrows);
  sum_kernel<<<1, 256, 0, stream>>>(lossrows, out);
}